// Round 1
// 587.187 us; speedup vs baseline: 1.0414x; 1.0414x over previous
//
#include <hip/hip_runtime.h>

typedef __bf16 bf16x8 __attribute__((ext_vector_type(8)));
typedef __bf16 bf16x4 __attribute__((ext_vector_type(4)));
typedef float  f32x4  __attribute__((ext_vector_type(4)));

static constexpr int Bb = 4, T = 8192, H = 1024, R = 1024;
static constexpr int BT = Bb * T;   // 32768 rows
static constexpr int N1 = 2 * R;    // 2048 (z|h columns)
static constexpr int CH = 64;       // scan chunks
static constexpr int L  = T / CH;   // 128 steps/chunk

// ---- async global -> LDS (16B per lane, wave-uniform LDS base) ----
__device__ __forceinline__ void g2lds16(const void* g, void* l) {
  __builtin_amdgcn_global_load_lds(
      (const __attribute__((address_space(1))) unsigned int*)g,
      (__attribute__((address_space(3))) unsigned int*)l, 16, 0, 0);
}

// ---- simple f32 -> bf16 cast (weights) ----
__global__ __launch_bounds__(256) void cast_f32_bf16(const float* __restrict__ in,
                                                     __bf16* __restrict__ out, int n4) {
  int i = blockIdx.x * 256 + threadIdx.x;
  if (i >= n4) return;
  const f32x4 v = *(const f32x4*)(in + (size_t)i * 4);
  bf16x4 o;
  o[0] = (__bf16)v[0]; o[1] = (__bf16)v[1]; o[2] = (__bf16)v[2]; o[3] = (__bf16)v[3];
  *(bf16x4*)(out + (size_t)i * 4) = o;
}

// ---- residual causal depthwise conv + cast to bf16 ----
__global__ __launch_bounds__(256) void conv_residual_cast(const float* __restrict__ x,
                                                          const float* __restrict__ cw,
                                                          const float* __restrict__ cb,
                                                          __bf16* __restrict__ xc) {
  const size_t i4 = (size_t)blockIdx.x * 256 + threadIdx.x;
  const size_t v  = i4 * 4;                    // element index into [B,T,H]
  const int    h  = (int)(v & (size_t)(H - 1));
  const size_t bt = v >> 10;                   // /H
  const int    t  = (int)(bt & (size_t)(T - 1));
  f32x4 acc = *(const f32x4*)(cb + h);
  const f32x4 xv = *(const f32x4*)(x + v);
#pragma unroll
  for (int i = 0; i < 4; ++i) {
    const int tt = t - 3 + i;
    if (tt >= 0) {
      const f32x4 xi = *(const f32x4*)(x + (bt - 3 + i) * H + h);
      const f32x4 wi = *(const f32x4*)(cw + i * H + h);
      acc += wi * xi;
    }
  }
  acc += xv;  // residual
  bf16x4 o;
  o[0] = (__bf16)acc[0]; o[1] = (__bf16)acc[1]; o[2] = (__bf16)acc[2]; o[3] = (__bf16)acc[3];
  *(bf16x4*)(xc + v) = o;
}

// ============================================================================
// 256x256 8-phase GEMM: C[M,N] = A[M,K] @ B[N,K]^T, bf16 in, fp32 acc.
// 512 threads = 8 waves (2M x 4N), per-wave 128x64 output via 16x16x32 MFMA.
// BK=64, double-buffered LDS (128 KiB), XOR-swizzled chunks (chunk ^= row&7)
// applied on the pre-swizzled GLOBAL source (LDS dest of global_load_lds is
// linear wave-contiguous).
//
// Per K-tile: 4 phases {ds_read 12xb128; stage 2xglobal_load_lds; s_barrier;
// lgkmcnt(0); setprio(1); 16 MFMA; setprio(0); [vmcnt(4) at ph4]; s_barrier}.
// Regions: A02=rows{0-63,128-191}, A13={64-127,192-255},
//          Bev={0-31,64-95,128-159,192-223}, Bod=Bev+32.
// Reads: ph1 A02+Bev, ph2 A13+Bev, ph3 A02+Bod, ph4 A13+Bod.
// Stage stream for tile t+1: Bev@ph3(t-1), A02@ph4(t-1), A13@ph1(t), Bod@ph2(t)
//  -> ph3/ph4 stage into the CURRENT buffer's dead Bev/A02 slots (tile t+2),
//     ph1/ph2 into the other buffer (tile t+1). Prefetch distance 5-6 phases.
// vmcnt(4) at ph4 guarantees everything tile t+1 reads; never drains to 0.
// ============================================================================

#define STG_A(buf, k0, ro) g2lds16(aBase + (size_t)(r + (ro)) * K + (k0), \
                                   &sA[buf][(w8 + (ro)) * 64])
#define STG_B(buf, k0, ro) g2lds16(bBase + (size_t)(rB + (ro)) * K + (k0), \
                                   &sB[buf][(w8B + (ro)) * 64])
#define STAGE_A02(buf, kt) do { const int k0_ = (kt) * 64; STG_A(buf, k0_, 0);  STG_A(buf, k0_, 128); } while (0)
#define STAGE_A13(buf, kt) do { const int k0_ = (kt) * 64; STG_A(buf, k0_, 64); STG_A(buf, k0_, 192); } while (0)
#define STAGE_BEV(buf, kt) do { const int k0_ = (kt) * 64; STG_B(buf, k0_, 0);  STG_B(buf, k0_, 128); } while (0)
#define STAGE_BOD(buf, kt) do { const int k0_ = (kt) * 64; STG_B(buf, k0_, 32); STG_B(buf, k0_, 160); } while (0)

#define PHASE(MQ, NQ, STAGE_STMT, W4) do {                                           \
    bf16x8 af_[4][2], bf_[2][2];                                                     \
    _Pragma("unroll") for (int i_ = 0; i_ < 4; ++i_) {                               \
      const int rt_ = aRowBase + (MQ) * 64 + i_ * 16;                                \
      _Pragma("unroll") for (int ks_ = 0; ks_ < 2; ++ks_)                            \
        af_[i_][ks_] = *(const bf16x8*)&sAc[rt_ * 64 + (((ks_ * 4 + kg) ^ (rt_ & 7)) * 8)]; \
    }                                                                                \
    _Pragma("unroll") for (int j_ = 0; j_ < 2; ++j_) {                               \
      const int rt_ = bRowBase + (NQ) * 32 + j_ * 16;                                \
      _Pragma("unroll") for (int ks_ = 0; ks_ < 2; ++ks_)                            \
        bf_[j_][ks_] = *(const bf16x8*)&sBc[rt_ * 64 + (((ks_ * 4 + kg) ^ (rt_ & 7)) * 8)]; \
    }                                                                                \
    STAGE_STMT;                                                                      \
    asm volatile("s_barrier" ::: "memory");                                          \
    asm volatile("s_waitcnt lgkmcnt(0)" ::: "memory");                               \
    __builtin_amdgcn_s_setprio(1);                                                   \
    _Pragma("unroll") for (int i_ = 0; i_ < 4; ++i_)                                 \
      _Pragma("unroll") for (int j_ = 0; j_ < 2; ++j_)                               \
        _Pragma("unroll") for (int ks_ = 0; ks_ < 2; ++ks_)                          \
          acc[(MQ) * 4 + i_][(NQ) * 2 + j_] = __builtin_amdgcn_mfma_f32_16x16x32_bf16( \
              af_[i_][ks_], bf_[j_][ks_], acc[(MQ) * 4 + i_][(NQ) * 2 + j_], 0, 0, 0); \
    __builtin_amdgcn_s_setprio(0);                                                   \
    if (W4) asm volatile("s_waitcnt vmcnt(4)" ::: "memory");                         \
    asm volatile("s_barrier" ::: "memory");                                          \
  } while (0)

template <typename OUT_T>
__global__ __launch_bounds__(512, 2) void gemm256(const __bf16* __restrict__ A,
                                                  const __bf16* __restrict__ Bm,
                                                  OUT_T* __restrict__ C,
                                                  int M, int N, int K, int nbx) {
  __shared__ __align__(16) __bf16 sA[2][256 * 64];
  __shared__ __align__(16) __bf16 sB[2][256 * 64];
  const int tid  = threadIdx.x;
  const int wave = tid >> 6;
  const int lane = tid & 63;
  const int wm = wave >> 2;  // 0..1
  const int wn = wave & 3;   // 0..3

  // T1: bijective XCD swizzle (both launches have nwg % 8 == 0)
  const int nwg = gridDim.x;
  int wg = blockIdx.x;
  wg = (wg & 7) * (nwg >> 3) + (wg >> 3);
  const int bm0 = (wg / nbx) * 256;
  const int bn0 = (wg % nbx) * 256;

  const int NT = K >> 6;  // K-tiles of 64

  // ---- staging geometry (per-thread constants) ----
  const int r   = tid >> 3;              // 0..63 row-in-round
  const int sgc = (tid & 7) ^ (r & 7);   // pre-swizzled source chunk
  const int rB  = r + (r & 32);          // B row pattern {0-31, 64-95}
  const int w8  = wave * 8;              // wave-uniform LDS row base
  const int w8B = w8 + (w8 & 32);
  const __bf16* aBase = A  + (size_t)bm0 * K + sgc * 8;
  const __bf16* bBase = Bm + (size_t)bn0 * K + sgc * 8;

  // ---- fragment-read geometry ----
  const int l15 = lane & 15;
  const int kg  = lane >> 4;             // k-group 0..3 (8 elems each)
  const int aRowBase = wm * 128 + l15;
  const int bRowBase = wn * 64 + l15;

  f32x4 acc[8][4] = {};

  // ---- prologue: stream positions ph3(-2)..ph4(-1) ----
  STAGE_BEV(0, 0);
  STAGE_A02(0, 0);
  STAGE_A13(0, 0);
  STAGE_BOD(0, 0);
  {
    const int k1 = NT > 1 ? 1 : 0;
    STAGE_BEV(1, k1);
    STAGE_A02(1, k1);
  }
  asm volatile("s_waitcnt vmcnt(4)" ::: "memory");  // tile 0 fully landed
  asm volatile("s_barrier" ::: "memory");

  for (int kt = 0; kt < NT; ++kt) {
    const int cur = kt & 1, nxt = cur ^ 1;
    const int kt1 = (kt + 1 < NT) ? kt + 1 : NT - 1;
    const int kt2 = (kt + 2 < NT) ? kt + 2 : NT - 1;
    const __bf16* sAc = sA[cur];
    const __bf16* sBc = sB[cur];
    PHASE(0, 0, STAGE_A13(nxt, kt1), 0);
    PHASE(1, 0, STAGE_BOD(nxt, kt1), 0);
    PHASE(0, 1, STAGE_BEV(cur, kt2), 0);
    PHASE(1, 1, STAGE_A02(cur, kt2), 1);
  }

  // ---- epilogue: 16x16 C/D layout: col = lane&15, row = (lane>>4)*4 + reg ----
  const int orow0 = bm0 + wm * 128 + kg * 4;
  const int ocol0 = bn0 + wn * 64 + l15;
#pragma unroll
  for (int mi = 0; mi < 8; ++mi)
#pragma unroll
    for (int nj = 0; nj < 4; ++nj) {
      const size_t rbase = (size_t)(orow0 + mi * 16);
#pragma unroll
      for (int rr = 0; rr < 4; ++rr)
        C[(rbase + rr) * N + (ocol0 + nj * 16)] = (OUT_T)acc[mi][nj][rr];
    }
}

// ---- scan pass 1: per-(b, chunk, r) aggregate (A,B): h_end = A*h_start + B ----
__global__ __launch_bounds__(256) void scan_pass1(const __bf16* __restrict__ zh,
                                                  float* __restrict__ aggA,
                                                  float* __restrict__ aggB) {
  const int r = blockIdx.x * 256 + threadIdx.x;
  const int c = blockIdx.y;
  const int b = blockIdx.z;
  size_t base = ((size_t)b * T + (size_t)c * L) * N1 + r;
  float Aacc = 1.f, Bacc = 0.f;
#pragma unroll 4
  for (int t = 0; t < L; ++t) {
    const float s  = (float)zh[base];
    const float hh = (float)zh[base + R];
    base += N1;
    const float z = 1.f / (1.f + __expf(-s));
    const float a = 1.f - z;
    Bacc = a * Bacc + z * hh;
    Aacc *= a;
  }
  const size_t o = ((size_t)b * CH + c) * R + r;
  aggA[o] = Aacc;
  aggB[o] = Bacc;
}

// ---- scan pass 2: scan the 64 chunk aggregates per (b,r); write carry-in per chunk ----
__global__ __launch_bounds__(256) void scan_pass2(const float* __restrict__ aggA,
                                                  const float* __restrict__ aggB,
                                                  float* __restrict__ carry) {
  const int idx = blockIdx.x * 256 + threadIdx.x;  // b*R + r
  const int b = idx >> 10;
  const int r = idx & (R - 1);
  float h = 0.f;
#pragma unroll 8
  for (int c = 0; c < CH; ++c) {
    const size_t o = ((size_t)b * CH + c) * R + r;
    carry[o] = h;
    h = aggA[o] * h + aggB[o];
  }
}

// ---- scan pass 3: apply carry, recompute gates, emit h_o (bf16) ----
__global__ __launch_bounds__(256) void scan_pass3(const __bf16* __restrict__ zh,
                                                  const float* __restrict__ carry,
                                                  __bf16* __restrict__ ho) {
  const int r = blockIdx.x * 256 + threadIdx.x;
  const int c = blockIdx.y;
  const int b = blockIdx.z;
  size_t base  = ((size_t)b * T + (size_t)c * L) * N1 + r;
  size_t obase = ((size_t)b * T + (size_t)c * L) * R + r;
  float h = carry[((size_t)b * CH + c) * R + r];
#pragma unroll 4
  for (int t = 0; t < L; ++t) {
    const float s  = (float)zh[base];
    const float hh = (float)zh[base + R];
    base += N1;
    const float z = 1.f / (1.f + __expf(-s));
    h = (1.f - z) * h + z * hh;
    ho[obase] = (__bf16)h;
    obase += R;
  }
}

extern "C" void kernel_launch(void* const* d_in, const int* in_sizes, int n_in,
                              void* d_out, int out_size, void* d_ws, size_t ws_size,
                              hipStream_t stream) {
  const float* x      = (const float*)d_in[0];
  const float* w_zh   = (const float*)d_in[1];
  const float* w_out  = (const float*)d_in[2];
  const float* conv_w = (const float*)d_in[3];
  const float* conv_b = (const float*)d_in[4];
  float* out = (float*)d_out;

  char* ws = (char*)d_ws;
  size_t off = 0;
  __bf16* wzh_b  = (__bf16*)(ws + off); off += (size_t)N1 * H * 2;        // 4 MiB
  __bf16* wout_b = (__bf16*)(ws + off); off += (size_t)H * R * 2;         // 2 MiB
  __bf16* xc     = (__bf16*)(ws + off); off += (size_t)BT * H * 2;        // 64 MiB
  __bf16* zh     = (__bf16*)(ws + off); off += (size_t)BT * N1 * 2;       // 128 MiB
  float*  aggA   = (float*)(ws + off);  off += (size_t)Bb * CH * R * 4;   // 1 MiB
  float*  aggB   = (float*)(ws + off);  off += (size_t)Bb * CH * R * 4;   // 1 MiB
  float*  carry  = (float*)(ws + off);  off += (size_t)Bb * CH * R * 4;   // 1 MiB
  __bf16* ho = xc;  // alias: xc is dead after GEMM1

  cast_f32_bf16<<<(N1 * H / 4 + 255) / 256, 256, 0, stream>>>(w_zh, wzh_b, N1 * H / 4);
  cast_f32_bf16<<<(H * R / 4 + 255) / 256, 256, 0, stream>>>(w_out, wout_b, H * R / 4);
  conv_residual_cast<<<BT * H / 4 / 256, 256, 0, stream>>>(x, conv_w, conv_b, xc);
  // GEMM1: [32768,1024] @ [2048,1024]^T -> zh ; grid 128*8 = 1024 blocks
  gemm256<__bf16><<<(BT / 256) * (N1 / 256), 512, 0, stream>>>(xc, wzh_b, zh, BT, N1, H, N1 / 256);
  scan_pass1<<<dim3(R / 256, CH, Bb), 256, 0, stream>>>(zh, aggA, aggB);
  scan_pass2<<<Bb * R / 256, 256, 0, stream>>>(aggA, aggB, carry);
  scan_pass3<<<dim3(R / 256, CH, Bb), 256, 0, stream>>>(zh, carry, ho);
  // GEMM2: [32768,1024] @ [1024,1024]^T -> out ; grid 128*4 = 512 blocks
  gemm256<float><<<(BT / 256) * (H / 256), 512, 0, stream>>>(ho, wout_b, out, BT, H, R, H / 256);
}